// Round 8
// baseline (32.158 us; speedup 1.0000x reference)
//
#include <hip/hip_runtime.h>

// LBP fused kernel: RGB->gray -> 3x3 binary-compare sum s -> 3x3 weighted LBP.
// Gray uses the exact FMA chain fma(b,.114, fma(g,.587, r*.2989)) -- bit-match
// with the harness's numpy (BLAS sgemv) reference; DO NOT change the formula.
//
// R7 was ~1.5x over the HBM floor: blocks only fetch during phase 1, and all
// blocks march the same barrier schedule in lockstep -> alternating VMEM-
// saturated / VMEM-idle windows. R8: 2-tile-per-block software pipeline
// (z and z+16). Tile B's 9 global_load_dwordx4 are issued into registers
// before tile A's compute phases, so B's HBM traffic flows during A's
// s/LBP compute. One shared gray buffer (B's gray store lands after A's
// gray is dead). LDS stays 19.6KB; +36 held VGPRs (~5 waves/SIMD).
//
// Schedule: issueA,storeGrayA | issueB,computeS_A | lbpA,storeGrayB |
//           computeS_B | lbpB   (4 barriers / 2 tiles)

#define TPB    256
#define TILE_X 64
#define TILE_Y 32
#define GROWS  36   // y0-2 .. y0+33
#define GCOLS  72   // x0-4 .. x0+67; col c <-> image x = x0-4+c
#define SROWS  34   // s row r <-> image y = y0-1+r
#define SCOLS  68   // s col c <-> image x = x0-1+c; cols 0..65 used
#define GQ     (GROWS * (GCOLS / 4))   // 648 quads
#define SQ     (SROWS * (SCOLS / 4))   // 578 quads

typedef float f32x4 __attribute__((ext_vector_type(4)));

__global__ __launch_bounds__(TPB, 5) void lbp_kernel(const float* __restrict__ in,
                                                     float* __restrict__ out) {
    __shared__ float grayS[GROWS * GCOLS];  // 10368 B
    __shared__ float sS[SROWS * SCOLS];     //  9248 B

    const int y0  = blockIdx.y * TILE_Y;
    const int x0  = blockIdx.x * TILE_X;
    const int tid = threadIdx.x;
    const int n0  = blockIdx.z;        // 0..15
    const int n1  = blockIdx.z + 16;   // 16..31

    f32x4 L[3][3];  // held raw RGB quads for the in-flight tile

    // Issue the 9 global loads for image n into L (no waiting here).
    auto issue = [&](int n) {
        #pragma unroll
        for (int k = 0; k < 3; ++k) {
            const int i = tid + k * TPB;
            if (i < GQ) {
                const int qy  = i / (GCOLS / 4);
                const int qx  = i - qy * (GCOLS / 4);
                const int gy  = y0 - 2 + qy;
                const int px0 = x0 - 4 + qx * 4;          // multiple of 4
                const bool okx = (unsigned)px0 < 512u;    // quad fully in/out
                const int  cy  = min(max(gy, 0), 511);
                const int  cx  = okx ? px0 : 0;
                const f32x4* p4 = reinterpret_cast<const f32x4*>(
                    in + ((size_t)(n * 512 + cy) * 512 + (size_t)cx) * 3);
                L[k][0] = p4[0];   // p0.r p0.g p0.b p1.r
                L[k][1] = p4[1];   // p1.g p1.b p2.r p2.g
                L[k][2] = p4[2];   // p2.b p3.r p3.g p3.b
            }
        }
    };

    // Convert held RGB quads to gray and store into grayS.
    auto store_gray = [&]() {
        #pragma unroll
        for (int k = 0; k < 3; ++k) {
            const int i = tid + k * TPB;
            if (i < GQ) {
                const int qy  = i / (GCOLS / 4);
                const int qx  = i - qy * (GCOLS / 4);
                const int gy  = y0 - 2 + qy;
                const int px0 = x0 - 4 + qx * 4;
                const bool ok = ((unsigned)gy < 512u) & ((unsigned)px0 < 512u);
                const f32x4 f0 = L[k][0], f1 = L[k][1], f2 = L[k][2];
                // Exact FMA chain matching BLAS sgemv accumulation (bit-exact).
                const float g0 = __builtin_fmaf(f0.z, 0.114f, __builtin_fmaf(f0.y, 0.587f, f0.x * 0.2989f));
                const float g1 = __builtin_fmaf(f1.y, 0.114f, __builtin_fmaf(f1.x, 0.587f, f0.w * 0.2989f));
                const float g2 = __builtin_fmaf(f2.x, 0.114f, __builtin_fmaf(f1.w, 0.587f, f1.z * 0.2989f));
                const float g3 = __builtin_fmaf(f2.w, 0.114f, __builtin_fmaf(f2.z, 0.587f, f2.y * 0.2989f));
                f32x4 gv;
                gv.x = ok ? g0 : 0.0f;
                gv.y = ok ? g1 : 0.0f;
                gv.z = ok ? g2 : 0.0f;
                gv.w = ok ? g3 : 0.0f;
                *reinterpret_cast<f32x4*>(&grayS[qy * GCOLS + qx * 4]) = gv;
            }
        }
    };

    // s = 3x3 compare-sum from grayS -> sS (4 px/thread, 6x ds_read_b128).
    auto compute_s = [&]() {
        #pragma unroll
        for (int k = 0; k < 3; ++k) {
            const int i = tid + k * TPB;
            if (i < SQ) {
                const int ly  = i / (SCOLS / 4);
                const int lx0 = (i - ly * (SCOLS / 4)) * 4;
                const f32x4 a0 = *reinterpret_cast<const f32x4*>(&grayS[(ly + 0) * GCOLS + lx0]);
                const f32x4 b0 = *reinterpret_cast<const f32x4*>(&grayS[(ly + 0) * GCOLS + lx0 + 4]);
                const f32x4 a1 = *reinterpret_cast<const f32x4*>(&grayS[(ly + 1) * GCOLS + lx0]);
                const f32x4 b1 = *reinterpret_cast<const f32x4*>(&grayS[(ly + 1) * GCOLS + lx0 + 4]);
                const f32x4 a2 = *reinterpret_cast<const f32x4*>(&grayS[(ly + 2) * GCOLS + lx0]);
                const f32x4 b2 = *reinterpret_cast<const f32x4*>(&grayS[(ly + 2) * GCOLS + lx0 + 4]);
                const float r0[8] = {a0.x, a0.y, a0.z, a0.w, b0.x, b0.y, b0.z, b0.w};
                const float r1[8] = {a1.x, a1.y, a1.z, a1.w, b1.x, b1.y, b1.z, b1.w};
                const float r2[8] = {a2.x, a2.y, a2.z, a2.w, b2.x, b2.y, b2.z, b2.w};
                float sv[4];
                #pragma unroll
                for (int e = 0; e < 4; ++e) {
                    const float c = r1[3 + e];
                    float s = 0.0f;
                    #pragma unroll
                    for (int d = 0; d < 3; ++d) {
                        s += (r0[2 + e + d] >= c) ? 1.0f : 0.0f;
                        s += (r1[2 + e + d] >= c) ? 1.0f : 0.0f;
                        s += (r2[2 + e + d] >= c) ? 1.0f : 0.0f;
                    }
                    const bool ok = ((unsigned)(y0 - 1 + ly) < 512u) &
                                    ((unsigned)(x0 - 1 + lx0 + e) < 512u);
                    sv[e] = ok ? s : 0.0f;
                }
                f32x4 svv;
                svv.x = sv[0]; svv.y = sv[1]; svv.z = sv[2]; svv.w = sv[3];
                *reinterpret_cast<f32x4*>(&sS[ly * SCOLS + lx0]) = svv;
            }
        }
    };

    // LBP cross-correlation from sS -> out (4 outputs/thread, 2 iters).
    auto lbp_store = [&](int n) {
        #pragma unroll
        for (int k = 0; k < 2; ++k) {
            const int i   = tid + k * TPB;
            const int py  = i / (TILE_X / 4);
            const int px0 = (i - py * (TILE_X / 4)) * 4;
            const f32x4 a0 = *reinterpret_cast<const f32x4*>(&sS[(py + 0) * SCOLS + px0]);
            const f32x4 b0 = *reinterpret_cast<const f32x4*>(&sS[(py + 0) * SCOLS + px0 + 4]);
            const f32x4 a1 = *reinterpret_cast<const f32x4*>(&sS[(py + 1) * SCOLS + px0]);
            const f32x4 b1 = *reinterpret_cast<const f32x4*>(&sS[(py + 1) * SCOLS + px0 + 4]);
            const f32x4 a2 = *reinterpret_cast<const f32x4*>(&sS[(py + 2) * SCOLS + px0]);
            const f32x4 b2 = *reinterpret_cast<const f32x4*>(&sS[(py + 2) * SCOLS + px0 + 4]);
            const float r0[8] = {a0.x, a0.y, a0.z, a0.w, b0.x, b0.y, b0.z, b0.w};
            const float r1[8] = {a1.x, a1.y, a1.z, a1.w, b1.x, b1.y, b1.z, b1.w};
            const float r2[8] = {a2.x, a2.y, a2.z, a2.w, b2.x, b2.y, b2.z, b2.w};
            f32x4 ov;
            #pragma unroll
            for (int e = 0; e < 4; ++e) {
                // Integer-valued fp32; sums exact regardless of order.
                ov[e] =   1.0f * r0[e] +   2.0f * r0[e + 1] +  4.0f * r0[e + 2]
                      + 128.0f * r1[e] +                        8.0f * r1[e + 2]
                      +  64.0f * r2[e] +  32.0f * r2[e + 1] + 16.0f * r2[e + 2];
            }
            f32x4* dst = reinterpret_cast<f32x4*>(
                out + (size_t)(n * 512 + (y0 + py)) * 512 + (size_t)(x0 + px0));
            __builtin_nontemporal_store(ov, dst);
        }
    };

    // ---- 2-tile pipeline ----
    issue(n0);
    store_gray();          // waits on n0 loads
    __syncthreads();

    issue(n1);             // n1 loads in flight during A's compute
    compute_s();           // grayS(A) -> sS(A)
    __syncthreads();

    lbp_store(n0);         // read sS(A)
    store_gray();          // overwrite grayS with B (A's gray is dead)
    __syncthreads();

    compute_s();           // grayS(B) -> sS(B) (A's sS reads done)
    __syncthreads();

    lbp_store(n1);
}

extern "C" void kernel_launch(void* const* d_in, const int* in_sizes, int n_in,
                              void* d_out, int out_size, void* d_ws, size_t ws_size,
                              hipStream_t stream) {
    const float* in = (const float*)d_in[0];
    float* out = (float*)d_out;
    dim3 grid(512 / TILE_X, 512 / TILE_Y, 16);  // 8 x 16 x 16 = 2048 blocks, 2 tiles each
    dim3 block(TPB);
    lbp_kernel<<<grid, block, 0, stream>>>(in, out);
}

// Round 9
// 31.063 us; speedup vs baseline: 1.0352x; 1.0352x over previous
//
#include <hip/hip_runtime.h>

// LBP fused kernel: RGB->gray -> 3x3 binary-compare sum s -> 3x3 weighted LBP.
// Gray uses the exact FMA chain fma(b,.114, fma(g,.587, r*.2989)) -- bit-match
// with the harness's numpy (BLAS sgemv) reference; DO NOT change the formula.
//
// R8 post-mortem: 2-tile pipeline neutral (blocks already desync) -> reverted.
// R9 theory: VALU-count-bound (~64 waves/CU x ~500 instr x 2cyc ~= 27us).
// Cuts: (1) phase-2 compares accumulate into an UNSIGNED int (cmp+addc, 2
// VALU) instead of float cndmask-add (3 VALU); (2) interior blocks (65%) are
// compile-time specialized with zero bounds logic; (3) phase-3 uses an
// explicit 7-FMA chain (exact: integer-valued fp32, pow2 weights).

#define TPB    256
#define TILE_X 64
#define TILE_Y 32
#define GROWS  36   // y0-2 .. y0+33
#define GCOLS  72   // x0-4 .. x0+67; col c <-> image x = x0-4+c
#define SROWS  34   // s row r <-> image y = y0-1+r
#define SCOLS  68   // s col c <-> image x = x0-1+c; cols 0..65 used
#define GQ     (GROWS * (GCOLS / 4))   // 648 quads
#define SQ     (SROWS * (SCOLS / 4))   // 578 quads

typedef float f32x4 __attribute__((ext_vector_type(4)));

template<bool EDGE>
__device__ __forceinline__ void do_tile(const float* __restrict__ in,
                                        float* __restrict__ out,
                                        float* __restrict__ grayS,
                                        float* __restrict__ sS,
                                        int n, int y0, int x0, int tid) {
    // ---- Phase 1: gray tile, 4-pixel quads, 3x global_load_dwordx4 each ----
    #pragma unroll
    for (int k = 0; k < 3; ++k) {
        const int i = tid + k * TPB;
        if (i < GQ) {
            const int qy  = i / (GCOLS / 4);
            const int qx  = i - qy * (GCOLS / 4);
            const int gy  = y0 - 2 + qy;
            const int px0 = x0 - 4 + qx * 4;          // multiple of 4
            int cy = gy, cx = px0;
            bool ok = true;
            if (EDGE) {
                const bool oky = (unsigned)gy  < 512u;
                const bool okx = (unsigned)px0 < 512u;   // quad fully in/out
                ok = oky & okx;
                cy = min(max(gy, 0), 511);
                cx = okx ? px0 : 0;
            }
            const f32x4* p4 = reinterpret_cast<const f32x4*>(
                in + ((size_t)(n * 512 + cy) * 512 + (size_t)cx) * 3);
            const f32x4 f0 = p4[0];   // p0.r p0.g p0.b p1.r
            const f32x4 f1 = p4[1];   // p1.g p1.b p2.r p2.g
            const f32x4 f2 = p4[2];   // p2.b p3.r p3.g p3.b
            // Exact FMA chain matching BLAS sgemv accumulation (bit-exact).
            float g0 = __builtin_fmaf(f0.z, 0.114f, __builtin_fmaf(f0.y, 0.587f, f0.x * 0.2989f));
            float g1 = __builtin_fmaf(f1.y, 0.114f, __builtin_fmaf(f1.x, 0.587f, f0.w * 0.2989f));
            float g2 = __builtin_fmaf(f2.x, 0.114f, __builtin_fmaf(f1.w, 0.587f, f1.z * 0.2989f));
            float g3 = __builtin_fmaf(f2.w, 0.114f, __builtin_fmaf(f2.z, 0.587f, f2.y * 0.2989f));
            f32x4 gv;
            if (EDGE) {
                gv.x = ok ? g0 : 0.0f;
                gv.y = ok ? g1 : 0.0f;
                gv.z = ok ? g2 : 0.0f;
                gv.w = ok ? g3 : 0.0f;
            } else {
                gv.x = g0; gv.y = g1; gv.z = g2; gv.w = g3;
            }
            *reinterpret_cast<f32x4*>(&grayS[qy * GCOLS + qx * 4]) = gv;
        }
    }
    __syncthreads();

    // ---- Phase 2: s = 3x3 compare-sum, 4 px/thread, uint accumulate ----
    #pragma unroll
    for (int k = 0; k < 3; ++k) {
        const int i = tid + k * TPB;
        if (i < SQ) {
            const int ly  = i / (SCOLS / 4);
            const int lx0 = (i - ly * (SCOLS / 4)) * 4;
            const f32x4 a0 = *reinterpret_cast<const f32x4*>(&grayS[(ly + 0) * GCOLS + lx0]);
            const f32x4 b0 = *reinterpret_cast<const f32x4*>(&grayS[(ly + 0) * GCOLS + lx0 + 4]);
            const f32x4 a1 = *reinterpret_cast<const f32x4*>(&grayS[(ly + 1) * GCOLS + lx0]);
            const f32x4 b1 = *reinterpret_cast<const f32x4*>(&grayS[(ly + 1) * GCOLS + lx0 + 4]);
            const f32x4 a2 = *reinterpret_cast<const f32x4*>(&grayS[(ly + 2) * GCOLS + lx0]);
            const f32x4 b2 = *reinterpret_cast<const f32x4*>(&grayS[(ly + 2) * GCOLS + lx0 + 4]);
            const float r0[8] = {a0.x, a0.y, a0.z, a0.w, b0.x, b0.y, b0.z, b0.w};
            const float r1[8] = {a1.x, a1.y, a1.z, a1.w, b1.x, b1.y, b1.z, b1.w};
            const float r2[8] = {a2.x, a2.y, a2.z, a2.w, b2.x, b2.y, b2.z, b2.w};
            float sv[4];
            #pragma unroll
            for (int e = 0; e < 4; ++e) {
                const float c = r1[3 + e];
                unsigned su = 0;
                #pragma unroll
                for (int d = 0; d < 3; ++d) {
                    su += (r0[2 + e + d] >= c);
                    su += (r1[2 + e + d] >= c);
                    su += (r2[2 + e + d] >= c);
                }
                float s = (float)su;
                if (EDGE) {
                    const bool ok = ((unsigned)(y0 - 1 + ly) < 512u) &
                                    ((unsigned)(x0 - 1 + lx0 + e) < 512u);
                    s = ok ? s : 0.0f;
                }
                sv[e] = s;
            }
            f32x4 svv;
            svv.x = sv[0]; svv.y = sv[1]; svv.z = sv[2]; svv.w = sv[3];
            *reinterpret_cast<f32x4*>(&sS[ly * SCOLS + lx0]) = svv;
        }
    }
    __syncthreads();

    // ---- Phase 3: LBP cross-correlation, 4 outputs/thread, 7-FMA chain ----
    // K = [[1,2,4],[128,0,8],[64,32,16]]
    #pragma unroll
    for (int k = 0; k < 2; ++k) {
        const int i   = tid + k * TPB;
        const int py  = i / (TILE_X / 4);
        const int px0 = (i - py * (TILE_X / 4)) * 4;
        const f32x4 a0 = *reinterpret_cast<const f32x4*>(&sS[(py + 0) * SCOLS + px0]);
        const f32x4 b0 = *reinterpret_cast<const f32x4*>(&sS[(py + 0) * SCOLS + px0 + 4]);
        const f32x4 a1 = *reinterpret_cast<const f32x4*>(&sS[(py + 1) * SCOLS + px0]);
        const f32x4 b1 = *reinterpret_cast<const f32x4*>(&sS[(py + 1) * SCOLS + px0 + 4]);
        const f32x4 a2 = *reinterpret_cast<const f32x4*>(&sS[(py + 2) * SCOLS + px0]);
        const f32x4 b2 = *reinterpret_cast<const f32x4*>(&sS[(py + 2) * SCOLS + px0 + 4]);
        const float r0[8] = {a0.x, a0.y, a0.z, a0.w, b0.x, b0.y, b0.z, b0.w};
        const float r1[8] = {a1.x, a1.y, a1.z, a1.w, b1.x, b1.y, b1.z, b1.w};
        const float r2[8] = {a2.x, a2.y, a2.z, a2.w, b2.x, b2.y, b2.z, b2.w};
        f32x4 ov;
        #pragma unroll
        for (int e = 0; e < 4; ++e) {
            // Integer-valued fp32, pow2 weights: exact in any order.
            float acc = __builtin_fmaf(2.0f,   r0[e + 1], r0[e]);
            acc = __builtin_fmaf(4.0f,   r0[e + 2], acc);
            acc = __builtin_fmaf(128.0f, r1[e],     acc);
            acc = __builtin_fmaf(8.0f,   r1[e + 2], acc);
            acc = __builtin_fmaf(64.0f,  r2[e],     acc);
            acc = __builtin_fmaf(32.0f,  r2[e + 1], acc);
            acc = __builtin_fmaf(16.0f,  r2[e + 2], acc);
            ov[e] = acc;
        }
        f32x4* dst = reinterpret_cast<f32x4*>(
            out + (size_t)(n * 512 + (y0 + py)) * 512 + (size_t)(x0 + px0));
        __builtin_nontemporal_store(ov, dst);
    }
}

__global__ __launch_bounds__(TPB) void lbp_kernel(const float* __restrict__ in,
                                                  float* __restrict__ out) {
    __shared__ float grayS[GROWS * GCOLS];  // 10368 B
    __shared__ float sS[SROWS * SCOLS];     //  9248 B

    const int n  = blockIdx.z;
    const int y0 = blockIdx.y * TILE_Y;
    const int x0 = blockIdx.x * TILE_X;
    const bool edge = (blockIdx.x == 0) | (blockIdx.x == gridDim.x - 1) |
                      (blockIdx.y == 0) | (blockIdx.y == gridDim.y - 1);
    if (edge)
        do_tile<true>(in, out, grayS, sS, n, y0, x0, threadIdx.x);
    else
        do_tile<false>(in, out, grayS, sS, n, y0, x0, threadIdx.x);
}

extern "C" void kernel_launch(void* const* d_in, const int* in_sizes, int n_in,
                              void* d_out, int out_size, void* d_ws, size_t ws_size,
                              hipStream_t stream) {
    const float* in = (const float*)d_in[0];
    float* out = (float*)d_out;
    dim3 grid(512 / TILE_X, 512 / TILE_Y, 32);  // 8 x 16 x 32 = 4096 blocks
    dim3 block(TPB);
    lbp_kernel<<<grid, block, 0, stream>>>(in, out);
}

// Round 10
// 28.283 us; speedup vs baseline: 1.1370x; 1.0983x over previous
//
#include <hip/hip_runtime.h>

// LBP fused: RGB->gray -> 3x3 binary-compare sum s -> 3x3 weighted LBP.
// Gray uses the exact FMA chain fma(b,.114, fma(g,.587, r*.2989)) -- bit-match
// with the harness's numpy (BLAS sgemv) reference; DO NOT change the formula.
//
// R8 (load-upfront pipeline) and R9 (VALU cuts) were both neutral at ~31us:
// not VALU-bound, not occupancy-bound, HBM unsaturated. R10 theory: the 48B-
// stride dwordx4 loads amplify TA/L1 granule requests 3x. Fix: stage raw RGB
// via global_load_lds with PACKED 16B/lane chunks (wave instr = contiguous
// 1KB). Raw rows padded to 1024B in LDS so chunk->row/col needs no division:
// row = waveId + 4j, global stride per j = 24576B. gray/s alias the raw
// buffer (barrier separated). LDS 36864B -> 4 blocks/CU. Plus XCD-bijective
// block swizzle for L2 halo locality.

#define TPB    256
#define TILE_X 64
#define TILE_Y 32
#define GROWS  36   // y0-2 .. y0+33
#define GCOLS  72   // col c <-> image x = x0-4+c
#define SROWS  34   // s row r <-> image y = y0-1+r
#define SCOLS  68   // s col c <-> image x = x0-1+c
#define GQ     (GROWS * (GCOLS / 4))   // 648 quads
#define SQ     (SROWS * (SCOLS / 4))   // 578 quads
#define RAW_FLOATS (GROWS * 256)       // 36 rows x 1024B = 36864 B
#define S_OFF  (GROWS * GCOLS)         // sS float offset (2592) after gray

typedef float f32x4 __attribute__((ext_vector_type(4)));

template<bool EDGE>
__device__ __forceinline__ void do_tile(const float* __restrict__ in,
                                        float* __restrict__ out,
                                        float* __restrict__ buf,
                                        int n, int y0, int x0, int tid) {
    float* grayS = buf;           // aliases raw rows 0..10367B (after barrier)
    float* sS    = buf + S_OFF;   // bytes 10368..19615 (raw dead by then)

    // ---- P0: packed staging, 9 x global_load_lds(16B) per thread ----
    // LDS raw row r at byte r*1024 (864B data + 160B pad). Chunk for thread
    // tid, iter j: LDS byte tid*16 + j*4096 -> row = (tid>>6)+4j,
    // colByte = (tid&63)*16.
    {
        const int r0   = tid >> 6;            // wave id = starting row
        const int col0 = (tid & 63) * 16;     // byte within padded row
        long gcb = (long)(x0 - 4) * 12 + col0; // byte within 6144B image row
        if (EDGE) gcb = gcb < 0 ? 0 : (gcb > 6128 ? 6128 : gcb);
        const char* base = (const char*)in;
        #pragma unroll
        for (int j = 0; j < 9; ++j) {
            int gy = y0 - 2 + r0 + 4 * j;
            if (EDGE) gy = min(max(gy, 0), 511);
            const char* ga = base + (size_t)(n * 512 + gy) * 6144 + gcb;
            char* la = (char*)buf + (size_t)(tid >> 6) * 1024 + (size_t)j * 4096;
            __builtin_amdgcn_global_load_lds(
                (const __attribute__((address_space(1))) void*)(const void*)ga,
                (__attribute__((address_space(3))) void*)(void*)la,
                16, 0, 0);
        }
    }
    __syncthreads();  // drains vmcnt; raw tile complete

    // ---- P1a: gray for own quad from raw LDS (3x ds_read_b128) ----
    f32x4 gv[3];
    #pragma unroll
    for (int k = 0; k < 3; ++k) {
        const int i = tid + k * TPB;
        if (i < GQ) {
            const int qy = i / (GCOLS / 4);
            const int qx = i - qy * (GCOLS / 4);
            const float* rp = buf + qy * 256 + qx * 12;
            const f32x4 f0 = *reinterpret_cast<const f32x4*>(rp);     // r g b r
            const f32x4 f1 = *reinterpret_cast<const f32x4*>(rp + 4); // g b r g
            const f32x4 f2 = *reinterpret_cast<const f32x4*>(rp + 8); // b r g b
            // Exact FMA chain matching BLAS sgemv accumulation (bit-exact).
            float g0 = __builtin_fmaf(f0.z, 0.114f, __builtin_fmaf(f0.y, 0.587f, f0.x * 0.2989f));
            float g1 = __builtin_fmaf(f1.y, 0.114f, __builtin_fmaf(f1.x, 0.587f, f0.w * 0.2989f));
            float g2 = __builtin_fmaf(f2.x, 0.114f, __builtin_fmaf(f1.w, 0.587f, f1.z * 0.2989f));
            float g3 = __builtin_fmaf(f2.w, 0.114f, __builtin_fmaf(f2.z, 0.587f, f2.y * 0.2989f));
            f32x4 g;
            if (EDGE) {
                const int gy  = y0 - 2 + qy;
                const int px0 = x0 - 4 + qx * 4;
                const bool ok = ((unsigned)gy < 512u) & ((unsigned)px0 < 512u);
                g.x = ok ? g0 : 0.0f;
                g.y = ok ? g1 : 0.0f;
                g.z = ok ? g2 : 0.0f;
                g.w = ok ? g3 : 0.0f;
            } else {
                g.x = g0; g.y = g1; g.z = g2; g.w = g3;
            }
            gv[k] = g;
        }
    }
    __syncthreads();  // all raw reads done; safe to overwrite with gray

    // ---- P1b: write gray tile (aliases raw base) ----
    #pragma unroll
    for (int k = 0; k < 3; ++k) {
        const int i = tid + k * TPB;
        if (i < GQ) {
            const int qy = i / (GCOLS / 4);
            const int qx = i - qy * (GCOLS / 4);
            *reinterpret_cast<f32x4*>(&grayS[qy * GCOLS + qx * 4]) = gv[k];
        }
    }
    __syncthreads();

    // ---- P2: s = 3x3 compare-sum, 4 px/thread, uint accumulate ----
    #pragma unroll
    for (int k = 0; k < 3; ++k) {
        const int i = tid + k * TPB;
        if (i < SQ) {
            const int ly  = i / (SCOLS / 4);
            const int lx0 = (i - ly * (SCOLS / 4)) * 4;
            const f32x4 a0 = *reinterpret_cast<const f32x4*>(&grayS[(ly + 0) * GCOLS + lx0]);
            const f32x4 b0 = *reinterpret_cast<const f32x4*>(&grayS[(ly + 0) * GCOLS + lx0 + 4]);
            const f32x4 a1 = *reinterpret_cast<const f32x4*>(&grayS[(ly + 1) * GCOLS + lx0]);
            const f32x4 b1 = *reinterpret_cast<const f32x4*>(&grayS[(ly + 1) * GCOLS + lx0 + 4]);
            const f32x4 a2 = *reinterpret_cast<const f32x4*>(&grayS[(ly + 2) * GCOLS + lx0]);
            const f32x4 b2 = *reinterpret_cast<const f32x4*>(&grayS[(ly + 2) * GCOLS + lx0 + 4]);
            const float r0[8] = {a0.x, a0.y, a0.z, a0.w, b0.x, b0.y, b0.z, b0.w};
            const float r1[8] = {a1.x, a1.y, a1.z, a1.w, b1.x, b1.y, b1.z, b1.w};
            const float r2[8] = {a2.x, a2.y, a2.z, a2.w, b2.x, b2.y, b2.z, b2.w};
            float sv[4];
            #pragma unroll
            for (int e = 0; e < 4; ++e) {
                const float c = r1[3 + e];
                unsigned su = 0;
                #pragma unroll
                for (int d = 0; d < 3; ++d) {
                    su += (r0[2 + e + d] >= c);
                    su += (r1[2 + e + d] >= c);
                    su += (r2[2 + e + d] >= c);
                }
                float s = (float)su;
                if (EDGE) {
                    const bool ok = ((unsigned)(y0 - 1 + ly) < 512u) &
                                    ((unsigned)(x0 - 1 + lx0 + e) < 512u);
                    s = ok ? s : 0.0f;
                }
                sv[e] = s;
            }
            f32x4 svv;
            svv.x = sv[0]; svv.y = sv[1]; svv.z = sv[2]; svv.w = sv[3];
            *reinterpret_cast<f32x4*>(&sS[ly * SCOLS + lx0]) = svv;
        }
    }
    __syncthreads();

    // ---- P3: LBP cross-correlation, 4 outputs/thread, 7-FMA chain ----
    // K = [[1,2,4],[128,0,8],[64,32,16]]
    #pragma unroll
    for (int k = 0; k < 2; ++k) {
        const int i   = tid + k * TPB;
        const int py  = i / (TILE_X / 4);
        const int px0 = (i - py * (TILE_X / 4)) * 4;
        const f32x4 a0 = *reinterpret_cast<const f32x4*>(&sS[(py + 0) * SCOLS + px0]);
        const f32x4 b0 = *reinterpret_cast<const f32x4*>(&sS[(py + 0) * SCOLS + px0 + 4]);
        const f32x4 a1 = *reinterpret_cast<const f32x4*>(&sS[(py + 1) * SCOLS + px0]);
        const f32x4 b1 = *reinterpret_cast<const f32x4*>(&sS[(py + 1) * SCOLS + px0 + 4]);
        const f32x4 a2 = *reinterpret_cast<const f32x4*>(&sS[(py + 2) * SCOLS + px0]);
        const f32x4 b2 = *reinterpret_cast<const f32x4*>(&sS[(py + 2) * SCOLS + px0 + 4]);
        const float r0[8] = {a0.x, a0.y, a0.z, a0.w, b0.x, b0.y, b0.z, b0.w};
        const float r1[8] = {a1.x, a1.y, a1.z, a1.w, b1.x, b1.y, b1.z, b1.w};
        const float r2[8] = {a2.x, a2.y, a2.z, a2.w, b2.x, b2.y, b2.z, b2.w};
        f32x4 ov;
        #pragma unroll
        for (int e = 0; e < 4; ++e) {
            // Integer-valued fp32, pow2 weights: exact in any order.
            float acc = __builtin_fmaf(2.0f,   r0[e + 1], r0[e]);
            acc = __builtin_fmaf(4.0f,   r0[e + 2], acc);
            acc = __builtin_fmaf(128.0f, r1[e],     acc);
            acc = __builtin_fmaf(8.0f,   r1[e + 2], acc);
            acc = __builtin_fmaf(64.0f,  r2[e],     acc);
            acc = __builtin_fmaf(32.0f,  r2[e + 1], acc);
            acc = __builtin_fmaf(16.0f,  r2[e + 2], acc);
            ov[e] = acc;
        }
        f32x4* dst = reinterpret_cast<f32x4*>(
            out + (size_t)(n * 512 + (y0 + py)) * 512 + (size_t)(x0 + px0));
        __builtin_nontemporal_store(ov, dst);
    }
}

__global__ __launch_bounds__(TPB) void lbp_kernel(const float* __restrict__ in,
                                                  float* __restrict__ out) {
    __shared__ float buf[RAW_FLOATS];   // 36864 B; raw / gray+s (aliased)

    // XCD-bijective swizzle: 4096 blocks % 8 XCDs == 0. Hardware round-robins
    // consecutive ids across XCDs; remap so each XCD owns 512 consecutive
    // logical tiles (4 whole images) -> halo re-reads hit local L2.
    const int id  = blockIdx.x;
    const int nid = (id & 7) * 512 + (id >> 3);
    const int n   = nid >> 7;          // image
    const int by  = (nid >> 3) & 15;
    const int bx  = nid & 7;
    const int y0  = by * TILE_Y;
    const int x0  = bx * TILE_X;
    const bool edge = (bx == 0) | (bx == 7) | (by == 0) | (by == 15);
    if (edge)
        do_tile<true>(in, out, buf, n, y0, x0, threadIdx.x);
    else
        do_tile<false>(in, out, buf, n, y0, x0, threadIdx.x);
}

extern "C" void kernel_launch(void* const* d_in, const int* in_sizes, int n_in,
                              void* d_out, int out_size, void* d_ws, size_t ws_size,
                              hipStream_t stream) {
    const float* in = (const float*)d_in[0];
    float* out = (float*)d_out;
    lbp_kernel<<<dim3(4096), dim3(TPB), 0, stream>>>(in, out);
}

// Round 11
// 26.223 us; speedup vs baseline: 1.2263x; 1.0786x over previous
//
#include <hip/hip_runtime.h>

// LBP fused: RGB->gray -> 3x3 binary-compare sum s -> 3x3 weighted LBP.
// Gray uses the exact FMA chain fma(b,.114, fma(g,.587, r*.2989)) -- bit-match
// with the harness's numpy (BLAS sgemv) reference; DO NOT change the formula.
//
// R10 (packed global_load_lds staging + XCD swizzle) = 28.3us (+9%).
// R11: (1) exec-mask staging to 54 lanes (54x16B = 864B = exactly one raw
// row of 72 px) -- kills the 160B/row padding over-fetch; (2) LDS row stride
// 1024 -> 864B => 31104B total => 5 blocks/CU (was 4), 20 waves/CU for more
// cross-block phase overlap.

#define TPB    256
#define TILE_X 64
#define TILE_Y 32
#define GROWS  36    // y0-2 .. y0+33
#define GCOLS  72    // col c <-> image x = x0-4+c
#define SROWS  34    // s row r <-> image y = y0-1+r
#define SCOLS  68    // s col c <-> image x = x0-1+c
#define GQ     (GROWS * (GCOLS / 4))   // 648 quads
#define SQ     (SROWS * (SCOLS / 4))   // 578 quads
#define ROWB   864                     // raw row stride bytes (= 72px * 12B)
#define ROWF   (ROWB / 4)              // 216 floats
#define RAW_FLOATS (GROWS * ROWF)      // 7776 floats = 31104 B
#define S_OFF  (GROWS * GCOLS)         // sS float offset (2592) after gray

typedef float f32x4 __attribute__((ext_vector_type(4)));

template<bool EDGE>
__device__ __forceinline__ void do_tile(const float* __restrict__ in,
                                        float* __restrict__ out,
                                        float* __restrict__ buf,
                                        int n, int y0, int x0, int tid) {
    float* grayS = buf;           // aliases raw (after barrier; 10368 B)
    float* sS    = buf + S_OFF;   // floats 2592.. (9248 B; raw dead by then)

    // ---- P0: packed staging, 54 active lanes x 16B = one 864B row ----
    // LDS raw row r at byte r*864. For wave w, iter j: row r = w + 4j,
    // wave-uniform LDS base = buf + r*864; lane deposits at base + lane*16.
    {
        const int lane = tid & 63;
        const int w    = tid >> 6;            // wave id = starting row
        if (lane < 54) {
            long gcb = (long)(x0 - 4) * 12 + lane * 16;  // byte in 6144B row
            if (EDGE) gcb = gcb < 0 ? 0 : (gcb > 6128 ? 6128 : gcb);
            const char* base = (const char*)in;
            #pragma unroll
            for (int j = 0; j < 9; ++j) {
                int gy = y0 - 2 + w + 4 * j;
                if (EDGE) gy = min(max(gy, 0), 511);
                const char* ga = base + (size_t)(n * 512 + gy) * 6144 + gcb;
                char* la = (char*)buf + (size_t)w * ROWB + (size_t)j * (4 * ROWB);
                __builtin_amdgcn_global_load_lds(
                    (const __attribute__((address_space(1))) void*)(const void*)ga,
                    (__attribute__((address_space(3))) void*)(void*)la,
                    16, 0, 0);
            }
        }
    }
    __syncthreads();  // drains vmcnt; raw tile complete

    // ---- P1a: gray for own quad from raw LDS (3x ds_read_b128) ----
    f32x4 gv[3];
    #pragma unroll
    for (int k = 0; k < 3; ++k) {
        const int i = tid + k * TPB;
        if (i < GQ) {
            const int qy = i / (GCOLS / 4);
            const int qx = i - qy * (GCOLS / 4);
            const float* rp = buf + qy * ROWF + qx * 12;
            const f32x4 f0 = *reinterpret_cast<const f32x4*>(rp);     // r g b r
            const f32x4 f1 = *reinterpret_cast<const f32x4*>(rp + 4); // g b r g
            const f32x4 f2 = *reinterpret_cast<const f32x4*>(rp + 8); // b r g b
            // Exact FMA chain matching BLAS sgemv accumulation (bit-exact).
            float g0 = __builtin_fmaf(f0.z, 0.114f, __builtin_fmaf(f0.y, 0.587f, f0.x * 0.2989f));
            float g1 = __builtin_fmaf(f1.y, 0.114f, __builtin_fmaf(f1.x, 0.587f, f0.w * 0.2989f));
            float g2 = __builtin_fmaf(f2.x, 0.114f, __builtin_fmaf(f1.w, 0.587f, f1.z * 0.2989f));
            float g3 = __builtin_fmaf(f2.w, 0.114f, __builtin_fmaf(f2.z, 0.587f, f2.y * 0.2989f));
            f32x4 g;
            if (EDGE) {
                const int gy  = y0 - 2 + qy;
                const int px0 = x0 - 4 + qx * 4;
                const bool ok = ((unsigned)gy < 512u) & ((unsigned)px0 < 512u);
                g.x = ok ? g0 : 0.0f;
                g.y = ok ? g1 : 0.0f;
                g.z = ok ? g2 : 0.0f;
                g.w = ok ? g3 : 0.0f;
            } else {
                g.x = g0; g.y = g1; g.z = g2; g.w = g3;
            }
            gv[k] = g;
        }
    }
    __syncthreads();  // all raw reads done; safe to overwrite with gray

    // ---- P1b: write gray tile (aliases raw base) ----
    #pragma unroll
    for (int k = 0; k < 3; ++k) {
        const int i = tid + k * TPB;
        if (i < GQ) {
            const int qy = i / (GCOLS / 4);
            const int qx = i - qy * (GCOLS / 4);
            *reinterpret_cast<f32x4*>(&grayS[qy * GCOLS + qx * 4]) = gv[k];
        }
    }
    __syncthreads();

    // ---- P2: s = 3x3 compare-sum, 4 px/thread, uint accumulate ----
    #pragma unroll
    for (int k = 0; k < 3; ++k) {
        const int i = tid + k * TPB;
        if (i < SQ) {
            const int ly  = i / (SCOLS / 4);
            const int lx0 = (i - ly * (SCOLS / 4)) * 4;
            const f32x4 a0 = *reinterpret_cast<const f32x4*>(&grayS[(ly + 0) * GCOLS + lx0]);
            const f32x4 b0 = *reinterpret_cast<const f32x4*>(&grayS[(ly + 0) * GCOLS + lx0 + 4]);
            const f32x4 a1 = *reinterpret_cast<const f32x4*>(&grayS[(ly + 1) * GCOLS + lx0]);
            const f32x4 b1 = *reinterpret_cast<const f32x4*>(&grayS[(ly + 1) * GCOLS + lx0 + 4]);
            const f32x4 a2 = *reinterpret_cast<const f32x4*>(&grayS[(ly + 2) * GCOLS + lx0]);
            const f32x4 b2 = *reinterpret_cast<const f32x4*>(&grayS[(ly + 2) * GCOLS + lx0 + 4]);
            const float r0[8] = {a0.x, a0.y, a0.z, a0.w, b0.x, b0.y, b0.z, b0.w};
            const float r1[8] = {a1.x, a1.y, a1.z, a1.w, b1.x, b1.y, b1.z, b1.w};
            const float r2[8] = {a2.x, a2.y, a2.z, a2.w, b2.x, b2.y, b2.z, b2.w};
            float sv[4];
            #pragma unroll
            for (int e = 0; e < 4; ++e) {
                const float c = r1[3 + e];
                unsigned su = 0;
                #pragma unroll
                for (int d = 0; d < 3; ++d) {
                    su += (r0[2 + e + d] >= c);
                    su += (r1[2 + e + d] >= c);
                    su += (r2[2 + e + d] >= c);
                }
                float s = (float)su;
                if (EDGE) {
                    const bool ok = ((unsigned)(y0 - 1 + ly) < 512u) &
                                    ((unsigned)(x0 - 1 + lx0 + e) < 512u);
                    s = ok ? s : 0.0f;
                }
                sv[e] = s;
            }
            f32x4 svv;
            svv.x = sv[0]; svv.y = sv[1]; svv.z = sv[2]; svv.w = sv[3];
            *reinterpret_cast<f32x4*>(&sS[ly * SCOLS + lx0]) = svv;
        }
    }
    __syncthreads();

    // ---- P3: LBP cross-correlation, 4 outputs/thread, 7-FMA chain ----
    // K = [[1,2,4],[128,0,8],[64,32,16]]
    #pragma unroll
    for (int k = 0; k < 2; ++k) {
        const int i   = tid + k * TPB;
        const int py  = i / (TILE_X / 4);
        const int px0 = (i - py * (TILE_X / 4)) * 4;
        const f32x4 a0 = *reinterpret_cast<const f32x4*>(&sS[(py + 0) * SCOLS + px0]);
        const f32x4 b0 = *reinterpret_cast<const f32x4*>(&sS[(py + 0) * SCOLS + px0 + 4]);
        const f32x4 a1 = *reinterpret_cast<const f32x4*>(&sS[(py + 1) * SCOLS + px0]);
        const f32x4 b1 = *reinterpret_cast<const f32x4*>(&sS[(py + 1) * SCOLS + px0 + 4]);
        const f32x4 a2 = *reinterpret_cast<const f32x4*>(&sS[(py + 2) * SCOLS + px0]);
        const f32x4 b2 = *reinterpret_cast<const f32x4*>(&sS[(py + 2) * SCOLS + px0 + 4]);
        const float r0[8] = {a0.x, a0.y, a0.z, a0.w, b0.x, b0.y, b0.z, b0.w};
        const float r1[8] = {a1.x, a1.y, a1.z, a1.w, b1.x, b1.y, b1.z, b1.w};
        const float r2[8] = {a2.x, a2.y, a2.z, a2.w, b2.x, b2.y, b2.z, b2.w};
        f32x4 ov;
        #pragma unroll
        for (int e = 0; e < 4; ++e) {
            // Integer-valued fp32, pow2 weights: exact in any order.
            float acc = __builtin_fmaf(2.0f,   r0[e + 1], r0[e]);
            acc = __builtin_fmaf(4.0f,   r0[e + 2], acc);
            acc = __builtin_fmaf(128.0f, r1[e],     acc);
            acc = __builtin_fmaf(8.0f,   r1[e + 2], acc);
            acc = __builtin_fmaf(64.0f,  r2[e],     acc);
            acc = __builtin_fmaf(32.0f,  r2[e + 1], acc);
            acc = __builtin_fmaf(16.0f,  r2[e + 2], acc);
            ov[e] = acc;
        }
        f32x4* dst = reinterpret_cast<f32x4*>(
            out + (size_t)(n * 512 + (y0 + py)) * 512 + (size_t)(x0 + px0));
        __builtin_nontemporal_store(ov, dst);
    }
}

__global__ __launch_bounds__(TPB) void lbp_kernel(const float* __restrict__ in,
                                                  float* __restrict__ out) {
    __shared__ float buf[RAW_FLOATS];   // 31104 B; raw, then gray+s (aliased)

    // XCD-bijective swizzle: 4096 % 8 == 0. Each XCD owns 512 consecutive
    // logical tiles (4 whole images) -> halo re-reads hit the local L2.
    const int id  = blockIdx.x;
    const int nid = (id & 7) * 512 + (id >> 3);
    const int n   = nid >> 7;          // image
    const int by  = (nid >> 3) & 15;
    const int bx  = nid & 7;
    const int y0  = by * TILE_Y;
    const int x0  = bx * TILE_X;
    const bool edge = (bx == 0) | (bx == 7) | (by == 0) | (by == 15);
    if (edge)
        do_tile<true>(in, out, buf, n, y0, x0, threadIdx.x);
    else
        do_tile<false>(in, out, buf, n, y0, x0, threadIdx.x);
}

extern "C" void kernel_launch(void* const* d_in, const int* in_sizes, int n_in,
                              void* d_out, int out_size, void* d_ws, size_t ws_size,
                              hipStream_t stream) {
    const float* in = (const float*)d_in[0];
    float* out = (float*)d_out;
    lbp_kernel<<<dim3(4096), dim3(TPB), 0, stream>>>(in, out);
}